// Round 22
// baseline (127.251 us; speedup 1.0000x reference)
//
#include <hip/hip_runtime.h>
#include <cstddef>

#define N_NODES 50000
#define N_EDGES 625000
#define DIM     128
#define R_REL   200
#define BN_EPS  1e-5f
#define SLOTS   64            // per-node edge slots; P(deg>64) ~ 1e-19
#define ND4     ((N_NODES * DIM) / 4)   // 1,600,000
#define R4      ((R_REL * DIM) / 4)     // 6,400
#define NBIN    8
#define NPB     (N_NODES / NBIN)        // 6250 nodes per bin
#define CNT_IDX(d) (((d) & 7) * NPB + ((d) >> 3))   // XCD-private cnt layout

// fused-kernel block ranges
#define NB_FILL  (2442 * NBIN)           // 19536: 8 binned passes over edges
#define NB_CONV  3200                    // x/r -> bf16 convert
#define PREP_BASE (NB_FILL + NB_CONV)    // 22736
#define NB_PREP  128
#define ROUT_BASE (PREP_BASE + NB_PREP)  // 22864
#define NB_ROUT  100                     // 2 rows per block
#define NB_TOTAL (ROUT_BASE + NB_ROUT)   // 22964

typedef __bf16 bf16x8 __attribute__((ext_vector_type(8)));
typedef float  f32x4  __attribute__((ext_vector_type(4)));

__device__ __forceinline__ float bfu2f(unsigned int hi16) {
    return __uint_as_float(hi16);
}
__device__ __forceinline__ unsigned int f2bfr(float f) {  // RNE f32->bf16 (as ushort)
    unsigned int u = __float_as_uint(f);
    return (u + 0x7fffu + ((u >> 16) & 1u)) >> 16;
}

// ---------------------------------------------------------------------------
// init0: zero cnt; block 0 detects mask storage (byte vs int).
__global__ __launch_bounds__(256) void init0_kernel(
    int* __restrict__ cnt,
    const unsigned char* __restrict__ in_m, const unsigned char* __restrict__ out_m,
    int* __restrict__ flag) {
    int gid = blockIdx.x * 256 + threadIdx.x;
    if (gid < N_NODES) cnt[gid] = 0;
    if (blockIdx.x == 0) {
        int ok = (((int)in_m[threadIdx.x] + (int)out_m[threadIdx.x]) == 1) ? 1 : 0;
        __shared__ int sred[4];
        unsigned long long b = __ballot(ok);
        if ((threadIdx.x & 63) == 0) sred[threadIdx.x >> 6] = (b == ~0ULL) ? 1 : 0;
        __syncthreads();
        if (threadIdx.x == 0) *flag = sred[0] & sred[1] & sred[2] & sred[3];
    }
}

// ---------------------------------------------------------------------------
// fused front-end: XCD-binned slot_fill || x/r->bf16 convert || prep || rout.
// slot_fill: block b -> bin (b&7) (matches blockIdx%8 -> XCD round-robin),
// edge chunk (b>>3). Only edges with dst&7==bin are processed, so each bin's
// cnt region (CNT_IDX) and erec slot regions are touched by ONE XCD: atomics
// become L2-local, record lines fill before write-back.
__global__ __launch_bounds__(256) void fused_front_kernel(
    // slot_fill
    const int* __restrict__ dst, const int* __restrict__ src,
    const int* __restrict__ et, const float* __restrict__ norm,
    const void* __restrict__ omask, const int* __restrict__ flag,
    int* __restrict__ cnt, uint2* __restrict__ erec,
    // convert
    const float* __restrict__ x, ushort* __restrict__ xb,
    const float* __restrict__ rf, ushort* __restrict__ rb,
    // prep weights/biases
    const float* __restrict__ WO, const float* __restrict__ WI,
    const float* __restrict__ WS, const float* __restrict__ loop,
    const float* __restrict__ bS, const float* __restrict__ bO,
    const float* __restrict__ bI, ushort* __restrict__ Wb,
    float* __restrict__ bias0, float* __restrict__ bO3, float* __restrict__ bI3,
    float* __restrict__ colsum, float* __restrict__ colsq,
    // rout
    const float* __restrict__ WR, const float* __restrict__ bR,
    float* __restrict__ rout) {
    __shared__ float smem[256];   // prep: red[128]; rout: row2[2][128]
    int b = blockIdx.x, t = threadIdx.x;

    if (b < NB_FILL) {
        // ---- binned slot_fill ----
        int bin = b & 7;
        int e = (b >> 3) * 256 + t;
        if (e >= N_EDGES) return;
        int d = dst[e];
        if ((d & 7) != bin) return;
        int fl = *flag;
        bool m = fl ? (((const unsigned char*)omask)[e] != 0)
                    : (((const int*)omask)[e] != 0);
        int k = atomicAdd(&cnt[CNT_IDX(d)], 1);
        if (k < SLOTS) {
            unsigned w0 = (unsigned)src[e] | ((unsigned)et[e] << 16) | (m ? 0x80000000u : 0u);
            erec[(size_t)d * SLOTS + k] = make_uint2(w0, (unsigned)__float_as_int(norm[e]));
        }
    } else if (b < PREP_BASE) {
        // ---- x / r -> bf16 ----
        int cgid = (b - NB_FILL) * 256 + t;
        for (int i = cgid; i < ND4; i += NB_CONV * 256) {
            float4 v = ((const float4*)x)[i];
            ushort4 o;
            o.x = (ushort)f2bfr(v.x); o.y = (ushort)f2bfr(v.y);
            o.z = (ushort)f2bfr(v.z); o.w = (ushort)f2bfr(v.w);
            ((ushort4*)xb)[i] = o;
        }
        if (cgid < R4) {
            float4 v = ((const float4*)rf)[cgid];
            ushort4 o;
            o.x = (ushort)f2bfr(v.x); o.y = (ushort)f2bfr(v.y);
            o.z = (ushort)f2bfr(v.z); o.w = (ushort)f2bfr(v.w);
            ((ushort4*)rb)[cgid] = o;
        }
    } else if (b < ROUT_BASE) {
        // ---- prep weights + biases (+ zero colsum/colsq in block f==0) ----
        int f = b - PREP_BASE;
        const float third = 1.0f / 3.0f;
        for (int k = t; k < 384; k += 256) {
            float w;
            if (k < 128)      w = WS[f * DIM + k];
            else if (k < 256) w = WO[f * DIM + (k - 128)];
            else              w = WI[f * DIM + (k - 256)];
            Wb[f * 384 + k] = (ushort)f2bfr(w * third);
        }
        if (t < 128) smem[t] = loop[t] * WS[f * DIM + t];
        __syncthreads();
        for (int off = 64; off; off >>= 1) {
            if (t < off) smem[t] += smem[t + off];
            __syncthreads();
        }
        if (t == 0) bias0[f] = (bS[f] - smem[0]) * third;
        if (t == 1) bO3[f] = bO[f] * third;
        if (t == 2) bI3[f] = bI[f] * third;
        if (f == 0 && t >= 128) { colsum[t - 128] = 0.f; colsq[t - 128] = 0.f; }
    } else {
        // ---- rout: 2 rows per block ----
        float* row2 = smem;   // [2][128]
        int rloc = t >> 7, f = t & 127;
        int r = (b - ROUT_BASE) * 2 + rloc;
        row2[rloc * 128 + f] = rf[r * DIM + f];
        __syncthreads();
        float acc = bR[f];
        for (int k = 0; k < DIM; ++k) acc += row2[rloc * 128 + k] * WR[f * DIM + k];
        rout[r * DIM + f] = acc;
    }
}

// ---------------- aggregate: one wave per node, 8/4/2/1 ladder --------------
// deg/beg forced into SGPRs via readfirstlane -> scalar erec loads.
#define AGG_CALC(EX, EY, XW, RW)                                   \
    {                                                              \
        float nm = __uint_as_float(EY);                            \
        float fm = (float)((EX) >> 31);                            \
        float x0 = bfu2f((XW) << 16), x1 = bfu2f((XW) & 0xffff0000u); \
        float r0 = bfu2f((RW) << 16), r1 = bfu2f((RW) & 0xffff0000u); \
        float v0 = __builtin_fmaf(-nm, r0, x0);                    \
        float v1 = __builtin_fmaf(-nm, r1, x1);                    \
        aT0 += v0; aT1 += v1;                                      \
        aO0 = __builtin_fmaf(fm, v0, aO0);                         \
        aO1 = __builtin_fmaf(fm, v1, aO1);                         \
        cOf += fm;                                                 \
    }

__global__ __launch_bounds__(256, 8) void aggregate_kernel(
    const unsigned int* __restrict__ xb,   // bf16x2 per lane, [N][64]
    const unsigned int* __restrict__ rb,   // [R][64]
    const uint2* __restrict__ erec,
    const int* __restrict__ cnt,
    unsigned int* __restrict__ S_Ob, unsigned int* __restrict__ S_Ib,
    float* __restrict__ cntO, float* __restrict__ cntI) {
    int wv = threadIdx.x >> 6;
    unsigned lane = threadIdx.x & 63;
    int n = blockIdx.x * 4 + wv;
    if (n >= N_NODES) return;
    int deg = cnt[CNT_IDX(n)];
    deg = deg < SLOTS ? deg : SLOTS;
    deg = __builtin_amdgcn_readfirstlane(deg);           // SGPR
    int beg = __builtin_amdgcn_readfirstlane(n * SLOTS); // SGPR
    int end = beg + deg;

    float aT0 = 0.f, aT1 = 0.f, aO0 = 0.f, aO1 = 0.f, cOf = 0.f;

    int j = beg;
    for (; j + 7 < end; j += 8) {
        uint4 q01 = *(const uint4*)(erec + j);
        uint4 q23 = *(const uint4*)(erec + j + 2);
        uint4 q45 = *(const uint4*)(erec + j + 4);
        uint4 q67 = *(const uint4*)(erec + j + 6);
        unsigned xw0 = xb[((q01.x & 0xffffu) << 6) + lane];
        unsigned rw0 = rb[(((q01.x >> 16) & 0x7fffu) << 6) + lane];
        unsigned xw1 = xb[((q01.z & 0xffffu) << 6) + lane];
        unsigned rw1 = rb[(((q01.z >> 16) & 0x7fffu) << 6) + lane];
        unsigned xw2 = xb[((q23.x & 0xffffu) << 6) + lane];
        unsigned rw2 = rb[(((q23.x >> 16) & 0x7fffu) << 6) + lane];
        unsigned xw3 = xb[((q23.z & 0xffffu) << 6) + lane];
        unsigned rw3 = rb[(((q23.z >> 16) & 0x7fffu) << 6) + lane];
        unsigned xw4 = xb[((q45.x & 0xffffu) << 6) + lane];
        unsigned rw4 = rb[(((q45.x >> 16) & 0x7fffu) << 6) + lane];
        unsigned xw5 = xb[((q45.z & 0xffffu) << 6) + lane];
        unsigned rw5 = rb[(((q45.z >> 16) & 0x7fffu) << 6) + lane];
        unsigned xw6 = xb[((q67.x & 0xffffu) << 6) + lane];
        unsigned rw6 = rb[(((q67.x >> 16) & 0x7fffu) << 6) + lane];
        unsigned xw7 = xb[((q67.z & 0xffffu) << 6) + lane];
        unsigned rw7 = rb[(((q67.z >> 16) & 0x7fffu) << 6) + lane];
        AGG_CALC(q01.x, q01.y, xw0, rw0)
        AGG_CALC(q01.z, q01.w, xw1, rw1)
        AGG_CALC(q23.x, q23.y, xw2, rw2)
        AGG_CALC(q23.z, q23.w, xw3, rw3)
        AGG_CALC(q45.x, q45.y, xw4, rw4)
        AGG_CALC(q45.z, q45.w, xw5, rw5)
        AGG_CALC(q67.x, q67.y, xw6, rw6)
        AGG_CALC(q67.z, q67.w, xw7, rw7)
    }
    if (j + 3 < end) {   // 4-wide
        uint4 q01 = *(const uint4*)(erec + j);
        uint4 q23 = *(const uint4*)(erec + j + 2);
        unsigned xw0 = xb[((q01.x & 0xffffu) << 6) + lane];
        unsigned rw0 = rb[(((q01.x >> 16) & 0x7fffu) << 6) + lane];
        unsigned xw1 = xb[((q01.z & 0xffffu) << 6) + lane];
        unsigned rw1 = rb[(((q01.z >> 16) & 0x7fffu) << 6) + lane];
        unsigned xw2 = xb[((q23.x & 0xffffu) << 6) + lane];
        unsigned rw2 = rb[(((q23.x >> 16) & 0x7fffu) << 6) + lane];
        unsigned xw3 = xb[((q23.z & 0xffffu) << 6) + lane];
        unsigned rw3 = rb[(((q23.z >> 16) & 0x7fffu) << 6) + lane];
        AGG_CALC(q01.x, q01.y, xw0, rw0)
        AGG_CALC(q01.z, q01.w, xw1, rw1)
        AGG_CALC(q23.x, q23.y, xw2, rw2)
        AGG_CALC(q23.z, q23.w, xw3, rw3)
        j += 4;
    }
    if (j + 1 < end) {   // 2-wide
        uint4 q01 = *(const uint4*)(erec + j);
        unsigned xw0 = xb[((q01.x & 0xffffu) << 6) + lane];
        unsigned rw0 = rb[(((q01.x >> 16) & 0x7fffu) << 6) + lane];
        unsigned xw1 = xb[((q01.z & 0xffffu) << 6) + lane];
        unsigned rw1 = rb[(((q01.z >> 16) & 0x7fffu) << 6) + lane];
        AGG_CALC(q01.x, q01.y, xw0, rw0)
        AGG_CALC(q01.z, q01.w, xw1, rw1)
        j += 2;
    }
    if (j < end) {       // last single
        uint2 e0 = erec[j];
        unsigned xw0 = xb[((e0.x & 0xffffu) << 6) + lane];
        unsigned rw0 = rb[(((e0.x >> 16) & 0x7fffu) << 6) + lane];
        AGG_CALC(e0.x, e0.y, xw0, rw0)
    }

    float aI0 = aT0 - aO0, aI1 = aT1 - aO1;
    S_Ob[((unsigned)n << 6) + lane] = f2bfr(aO0) | (f2bfr(aO1) << 16);
    S_Ib[((unsigned)n << 6) + lane] = f2bfr(aI0) | (f2bfr(aI1) << 16);
    if (lane == 0) { cntO[n] = cOf; cntI[n] = (float)deg - cOf; }
}

// ---------------- MFMA GEMM (LDS-staged B) + bias + BN stats ----------------
__global__ __launch_bounds__(256, 4) void gemm_kernel(
    const ushort* __restrict__ xb, const ushort* __restrict__ S_Ob,
    const ushort* __restrict__ S_Ib, const ushort* __restrict__ Wb,
    const float* __restrict__ bias0, const float* __restrict__ bO3,
    const float* __restrict__ bI3, const float* __restrict__ cntO,
    const float* __restrict__ cntI, float* __restrict__ y,
    float* __restrict__ colsum, float* __restrict__ colsq) {
    __shared__ ushort Bs[128][136];   // 34.8 KB, row stride 272 B
    __shared__ float redS[4][128];
    __shared__ float redQ[4][128];

    int tid = threadIdx.x;
    int wv = tid >> 6, lane = tid & 63;
    int cl = lane & 15, kg = lane >> 4;
    int wrow0 = blockIdx.x * 64 + wv * 16;

    f32x4 acc[8];
#pragma unroll
    for (int cf = 0; cf < 8; ++cf) acc[cf] = (f32x4){0.f, 0.f, 0.f, 0.f};

    int rowA = wrow0 + cl;
    int rowc = rowA < N_NODES ? rowA : N_NODES - 1;
    const ushort* Abase[3] = {xb, S_Ob, S_Ib};

    for (int kq = 0; kq < 3; ++kq) {
        __syncthreads();
#pragma unroll
        for (int j = 0; j < 8; ++j) {
            int i = tid + j * 256;
            int col = i >> 4, k8 = (i & 15) << 3;
            uint4 w = *(const uint4*)(Wb + (size_t)col * 384 + kq * 128 + k8);
            *(uint4*)&Bs[col][k8] = w;
        }
        const ushort* Ap0 = Abase[kq] + (size_t)rowc * 128 + kg * 8;
        uint4 a4[4];
#pragma unroll
        for (int ks = 0; ks < 4; ++ks) a4[ks] = *(const uint4*)(Ap0 + ks * 32);
        __syncthreads();
#pragma unroll
        for (int ks = 0; ks < 4; ++ks) {
            bf16x8 af = __builtin_bit_cast(bf16x8, a4[ks]);
#pragma unroll
            for (int cf = 0; cf < 8; ++cf) {
                bf16x8 bv = __builtin_bit_cast(bf16x8,
                    *(const uint4*)&Bs[cf * 16 + cl][ks * 32 + kg * 8]);
                acc[cf] = __builtin_amdgcn_mfma_f32_16x16x32_bf16(af, bv, acc[cf], 0, 0, 0);
            }
        }
    }

    float b0a[8], boa[8], bia[8];
#pragma unroll
    for (int cf = 0; cf < 8; ++cf) {
        int col = cf * 16 + cl;
        b0a[cf] = bias0[col]; boa[cf] = bO3[col]; bia[cf] = bI3[col];
    }
    float cOv[4], cIv[4]; int rows[4]; bool rv[4];
#pragma unroll
    for (int r = 0; r < 4; ++r) {
        int row = wrow0 + kg * 4 + r;
        rows[r] = row; rv[r] = row < N_NODES;
        cOv[r] = rv[r] ? cntO[row] : 0.f;
        cIv[r] = rv[r] ? cntI[row] : 0.f;
    }
    float ps[8], pq[8];
#pragma unroll
    for (int cf = 0; cf < 8; ++cf) {
        float s = 0.f, q = 0.f;
        int col = cf * 16 + cl;
#pragma unroll
        for (int r = 0; r < 4; ++r) {
            if (rv[r]) {
                float v = acc[cf][r] + b0a[cf] + cOv[r] * boa[cf] + cIv[r] * bia[cf];
                y[(size_t)rows[r] * DIM + col] = v;
                s += v; q += v * v;
            }
        }
        s += __shfl_xor(s, 16);
        s += __shfl_xor(s, 32);
        q += __shfl_xor(q, 16);
        q += __shfl_xor(q, 32);
        ps[cf] = s; pq[cf] = q;
    }
    if (kg == 0) {
#pragma unroll
        for (int cf = 0; cf < 8; ++cf) {
            redS[wv][cf * 16 + cl] = ps[cf];
            redQ[wv][cf * 16 + cl] = pq[cf];
        }
    }
    __syncthreads();
    if (tid < 128) {
        float s = redS[0][tid] + redS[1][tid] + redS[2][tid] + redS[3][tid];
        float q = redQ[0][tid] + redQ[1][tid] + redQ[2][tid] + redQ[3][tid];
        atomicAdd(colsum + tid, s);
        atomicAdd(colsq + tid, q);
    }
}

// BN + tanh, in place on y.
__global__ __launch_bounds__(256) void bn_apply_kernel(
    float* __restrict__ y, const float* __restrict__ colsum, const float* __restrict__ colsq,
    const float* __restrict__ gamma, const float* __restrict__ beta) {
    __shared__ __align__(16) float sc[DIM];
    __shared__ __align__(16) float sh[DIM];
    int tid = threadIdx.x;
    if (tid < DIM) {
        float mean = colsum[tid] * (1.0f / N_NODES);
        float var  = colsq[tid] * (1.0f / N_NODES) - mean * mean;
        float s = rsqrtf(var + BN_EPS) * gamma[tid];
        sc[tid] = s;
        sh[tid] = beta[tid] - mean * s;
    }
    __syncthreads();
    const int total4 = N_NODES * 32;
    for (int i = blockIdx.x * 256 + tid; i < total4; i += gridDim.x * 256) {
        float4 s4 = ((const float4*)sc)[i & 31];
        float4 h4 = ((const float4*)sh)[i & 31];
        float4 v = ((float4*)y)[i];
        v.x = tanhf(v.x * s4.x + h4.x);
        v.y = tanhf(v.y * s4.y + h4.y);
        v.z = tanhf(v.z * s4.z + h4.z);
        v.w = tanhf(v.w * s4.w + h4.w);
        ((float4*)y)[i] = v;
    }
}

extern "C" void kernel_launch(void* const* d_in, const int* in_sizes, int n_in,
                              void* d_out, int out_size, void* d_ws, size_t ws_size,
                              hipStream_t stream) {
    const float* x        = (const float*)d_in[0];
    const float* r_feats  = (const float*)d_in[1];
    const int*   src      = (const int*)d_in[2];
    const int*   dst      = (const int*)d_in[3];
    const int*   etype    = (const int*)d_in[4];
    const float* norm     = (const float*)d_in[5];
    const void*  in_mask  = d_in[6];
    const void*  out_mask = d_in[7];
    const float* W_O_w    = (const float*)d_in[8];
    const float* W_O_b    = (const float*)d_in[9];
    const float* W_I_w    = (const float*)d_in[10];
    const float* W_I_b    = (const float*)d_in[11];
    const float* W_S_w    = (const float*)d_in[12];
    const float* W_S_b    = (const float*)d_in[13];
    const float* W_R_w    = (const float*)d_in[14];
    const float* W_R_b    = (const float*)d_in[15];
    const float* loop_rel = (const float*)d_in[16];
    const float* bn_gamma = (const float*)d_in[17];
    const float* bn_beta  = (const float*)d_in[18];

    const size_t ND = (size_t)N_NODES * DIM;
    char* p = (char*)d_ws;
    auto alloc = [&](size_t bytes) { void* r = (void*)p; p += (bytes + 255) & ~(size_t)255; return r; };

    ushort* S_Ob = (ushort*)alloc(ND * 2);
    ushort* S_Ib = (ushort*)alloc(ND * 2);
    ushort* xb   = (ushort*)alloc(ND * 2);
    ushort* rb   = (ushort*)alloc((size_t)R_REL * DIM * 2);
    uint2* erec  = (uint2*)alloc((size_t)N_NODES * SLOTS * 8);  // 25.6 MB slotted
    ushort* Wb   = (ushort*)alloc((size_t)DIM * 384 * 2);
    float* bias0 = (float*)alloc(DIM * 4);
    float* bO3   = (float*)alloc(DIM * 4);
    float* bI3   = (float*)alloc(DIM * 4);
    float* colsum= (float*)alloc(DIM * 4);
    float* colsq = (float*)alloc(DIM * 4);
    float* cntO  = (float*)alloc(N_NODES * 4);
    float* cntI  = (float*)alloc(N_NODES * 4);
    int*   cnt   = (int*)alloc(N_NODES * 4);
    int*   flag  = (int*)alloc(4);

    float* y    = (float*)d_out;               // n_out region, N*D floats
    float* rout = (float*)d_out + ND;          // r_out region, R*D floats

    init0_kernel<<<(N_NODES + 255) / 256, 256, 0, stream>>>(
        cnt, (const unsigned char*)in_mask, (const unsigned char*)out_mask, flag);

    fused_front_kernel<<<NB_TOTAL, 256, 0, stream>>>(
        dst, src, etype, norm, out_mask, flag, cnt, erec,
        x, xb, r_feats, rb,
        W_O_w, W_I_w, W_S_w, loop_rel, W_S_b, W_O_b, W_I_b,
        Wb, bias0, bO3, bI3, colsum, colsq,
        W_R_w, W_R_b, rout);

    aggregate_kernel<<<(N_NODES + 3) / 4, 256, 0, stream>>>(
        (const unsigned int*)xb, (const unsigned int*)rb, erec, cnt,
        (unsigned int*)S_Ob, (unsigned int*)S_Ib, cntO, cntI);

    gemm_kernel<<<(N_NODES + 63) / 64, 256, 0, stream>>>(
        xb, S_Ob, S_Ib, Wb, bias0, bO3, bI3, cntO, cntI, y, colsum, colsq);

    bn_apply_kernel<<<2048, 256, 0, stream>>>(y, colsum, colsq, bn_gamma, bn_beta);
}

// Round 23
// 125.566 us; speedup vs baseline: 1.0134x; 1.0134x over previous
//
#include <hip/hip_runtime.h>
#include <cstddef>

#define N_NODES 50000
#define N_EDGES 625000
#define DIM     128
#define R_REL   200
#define BN_EPS  1e-5f
#define SLOTS   64            // per-node edge slots; P(deg>64) ~ 1e-19
#define ND4     ((N_NODES * DIM) / 4)   // 1,600,000
#define R4      ((R_REL * DIM) / 4)     // 6,400

// fused-kernel block ranges
#define NB_FILL  2442                    // slot_fill: ceil(E/256)
#define NB_CONV  3200                    // x/r -> bf16 convert
#define PREP_BASE (NB_FILL + NB_CONV)    // 5642
#define NB_PREP  128
#define ROUT_BASE (PREP_BASE + NB_PREP)  // 5770
#define NB_ROUT  100                     // 2 rows per block
#define NB_TOTAL (ROUT_BASE + NB_ROUT)   // 5870

typedef __bf16 bf16x8 __attribute__((ext_vector_type(8)));
typedef float  f32x4  __attribute__((ext_vector_type(4)));

__device__ __forceinline__ float bfu2f(unsigned int hi16) {
    return __uint_as_float(hi16);
}
__device__ __forceinline__ unsigned int f2bfr(float f) {  // RNE f32->bf16 (as ushort)
    unsigned int u = __float_as_uint(f);
    return (u + 0x7fffu + ((u >> 16) & 1u)) >> 16;
}

// ---------------------------------------------------------------------------
// init0: zero cnt; block 0 detects mask storage (byte vs int).
__global__ __launch_bounds__(256) void init0_kernel(
    int* __restrict__ cnt,
    const unsigned char* __restrict__ in_m, const unsigned char* __restrict__ out_m,
    int* __restrict__ flag) {
    int gid = blockIdx.x * 256 + threadIdx.x;
    if (gid < N_NODES) cnt[gid] = 0;
    if (blockIdx.x == 0) {
        int ok = (((int)in_m[threadIdx.x] + (int)out_m[threadIdx.x]) == 1) ? 1 : 0;
        __shared__ int sred[4];
        unsigned long long b = __ballot(ok);
        if ((threadIdx.x & 63) == 0) sred[threadIdx.x >> 6] = (b == ~0ULL) ? 1 : 0;
        __syncthreads();
        if (threadIdx.x == 0) *flag = sred[0] & sred[1] & sred[2] & sred[3];
    }
}

// ---------------------------------------------------------------------------
// fused front-end: slot_fill || x/r->bf16 convert || prep_weights || rout.
__global__ __launch_bounds__(256) void fused_front_kernel(
    // slot_fill
    const int* __restrict__ dst, const int* __restrict__ src,
    const int* __restrict__ et, const float* __restrict__ norm,
    const void* __restrict__ omask, const int* __restrict__ flag,
    int* __restrict__ cnt, uint2* __restrict__ erec,
    // convert
    const float* __restrict__ x, ushort* __restrict__ xb,
    const float* __restrict__ rf, ushort* __restrict__ rb,
    // prep weights/biases
    const float* __restrict__ WO, const float* __restrict__ WI,
    const float* __restrict__ WS, const float* __restrict__ loop,
    const float* __restrict__ bS, const float* __restrict__ bO,
    const float* __restrict__ bI, ushort* __restrict__ Wb,
    float* __restrict__ bias0, float* __restrict__ bO3, float* __restrict__ bI3,
    float* __restrict__ colsum, float* __restrict__ colsq,
    // rout
    const float* __restrict__ WR, const float* __restrict__ bR,
    float* __restrict__ rout) {
    __shared__ float smem[256];   // prep: red[128]; rout: row2[2][128]
    int b = blockIdx.x, t = threadIdx.x;

    if (b < NB_FILL) {
        // ---- slot_fill ----
        int e = b * 256 + t;
        if (e >= N_EDGES) return;
        int fl = *flag;
        bool m = fl ? (((const unsigned char*)omask)[e] != 0)
                    : (((const int*)omask)[e] != 0);
        int d = dst[e];
        int k = atomicAdd(&cnt[d], 1);
        if (k < SLOTS) {
            unsigned w0 = (unsigned)src[e] | ((unsigned)et[e] << 16) | (m ? 0x80000000u : 0u);
            erec[(size_t)d * SLOTS + k] = make_uint2(w0, (unsigned)__float_as_int(norm[e]));
        }
    } else if (b < PREP_BASE) {
        // ---- x / r -> bf16 ----
        int cgid = (b - NB_FILL) * 256 + t;
        for (int i = cgid; i < ND4; i += NB_CONV * 256) {
            float4 v = ((const float4*)x)[i];
            ushort4 o;
            o.x = (ushort)f2bfr(v.x); o.y = (ushort)f2bfr(v.y);
            o.z = (ushort)f2bfr(v.z); o.w = (ushort)f2bfr(v.w);
            ((ushort4*)xb)[i] = o;
        }
        if (cgid < R4) {
            float4 v = ((const float4*)rf)[cgid];
            ushort4 o;
            o.x = (ushort)f2bfr(v.x); o.y = (ushort)f2bfr(v.y);
            o.z = (ushort)f2bfr(v.z); o.w = (ushort)f2bfr(v.w);
            ((ushort4*)rb)[cgid] = o;
        }
    } else if (b < ROUT_BASE) {
        // ---- prep weights + biases (+ zero colsum/colsq in block f==0) ----
        int f = b - PREP_BASE;
        const float third = 1.0f / 3.0f;
        for (int k = t; k < 384; k += 256) {
            float w;
            if (k < 128)      w = WS[f * DIM + k];
            else if (k < 256) w = WO[f * DIM + (k - 128)];
            else              w = WI[f * DIM + (k - 256)];
            Wb[f * 384 + k] = (ushort)f2bfr(w * third);
        }
        if (t < 128) smem[t] = loop[t] * WS[f * DIM + t];
        __syncthreads();
        for (int off = 64; off; off >>= 1) {
            if (t < off) smem[t] += smem[t + off];
            __syncthreads();
        }
        if (t == 0) bias0[f] = (bS[f] - smem[0]) * third;
        if (t == 1) bO3[f] = bO[f] * third;
        if (t == 2) bI3[f] = bI[f] * third;
        if (f == 0 && t >= 128) { colsum[t - 128] = 0.f; colsq[t - 128] = 0.f; }
    } else {
        // ---- rout: 2 rows per block ----
        float* row2 = smem;   // [2][128]
        int rloc = t >> 7, f = t & 127;
        int r = (b - ROUT_BASE) * 2 + rloc;
        row2[rloc * 128 + f] = rf[r * DIM + f];
        __syncthreads();
        float acc = bR[f];
        for (int k = 0; k < DIM; ++k) acc += row2[rloc * 128 + k] * WR[f * DIM + k];
        rout[r * DIM + f] = acc;
    }
}

// ---------------- aggregate: one wave per node, 8/4/2/1 ladder --------------
// deg/beg forced into SGPRs via readfirstlane -> scalar erec loads.
#define AGG_CALC(EX, EY, XW, RW)                                   \
    {                                                              \
        float nm = __uint_as_float(EY);                            \
        float fm = (float)((EX) >> 31);                            \
        float x0 = bfu2f((XW) << 16), x1 = bfu2f((XW) & 0xffff0000u); \
        float r0 = bfu2f((RW) << 16), r1 = bfu2f((RW) & 0xffff0000u); \
        float v0 = __builtin_fmaf(-nm, r0, x0);                    \
        float v1 = __builtin_fmaf(-nm, r1, x1);                    \
        aT0 += v0; aT1 += v1;                                      \
        aO0 = __builtin_fmaf(fm, v0, aO0);                         \
        aO1 = __builtin_fmaf(fm, v1, aO1);                         \
        cOf += fm;                                                 \
    }

__global__ __launch_bounds__(256, 8) void aggregate_kernel(
    const unsigned int* __restrict__ xb,   // bf16x2 per lane, [N][64]
    const unsigned int* __restrict__ rb,   // [R][64]
    const uint2* __restrict__ erec,
    const int* __restrict__ cnt,
    unsigned int* __restrict__ S_Ob, unsigned int* __restrict__ S_Ib,
    float* __restrict__ cntO, float* __restrict__ cntI) {
    int wv = threadIdx.x >> 6;
    unsigned lane = threadIdx.x & 63;
    int n = blockIdx.x * 4 + wv;
    if (n >= N_NODES) return;
    int deg = cnt[n];
    deg = deg < SLOTS ? deg : SLOTS;
    deg = __builtin_amdgcn_readfirstlane(deg);           // SGPR
    int beg = __builtin_amdgcn_readfirstlane(n * SLOTS); // SGPR
    int end = beg + deg;

    float aT0 = 0.f, aT1 = 0.f, aO0 = 0.f, aO1 = 0.f, cOf = 0.f;

    int j = beg;
    for (; j + 7 < end; j += 8) {
        uint4 q01 = *(const uint4*)(erec + j);
        uint4 q23 = *(const uint4*)(erec + j + 2);
        uint4 q45 = *(const uint4*)(erec + j + 4);
        uint4 q67 = *(const uint4*)(erec + j + 6);
        unsigned xw0 = xb[((q01.x & 0xffffu) << 6) + lane];
        unsigned rw0 = rb[(((q01.x >> 16) & 0x7fffu) << 6) + lane];
        unsigned xw1 = xb[((q01.z & 0xffffu) << 6) + lane];
        unsigned rw1 = rb[(((q01.z >> 16) & 0x7fffu) << 6) + lane];
        unsigned xw2 = xb[((q23.x & 0xffffu) << 6) + lane];
        unsigned rw2 = rb[(((q23.x >> 16) & 0x7fffu) << 6) + lane];
        unsigned xw3 = xb[((q23.z & 0xffffu) << 6) + lane];
        unsigned rw3 = rb[(((q23.z >> 16) & 0x7fffu) << 6) + lane];
        unsigned xw4 = xb[((q45.x & 0xffffu) << 6) + lane];
        unsigned rw4 = rb[(((q45.x >> 16) & 0x7fffu) << 6) + lane];
        unsigned xw5 = xb[((q45.z & 0xffffu) << 6) + lane];
        unsigned rw5 = rb[(((q45.z >> 16) & 0x7fffu) << 6) + lane];
        unsigned xw6 = xb[((q67.x & 0xffffu) << 6) + lane];
        unsigned rw6 = rb[(((q67.x >> 16) & 0x7fffu) << 6) + lane];
        unsigned xw7 = xb[((q67.z & 0xffffu) << 6) + lane];
        unsigned rw7 = rb[(((q67.z >> 16) & 0x7fffu) << 6) + lane];
        AGG_CALC(q01.x, q01.y, xw0, rw0)
        AGG_CALC(q01.z, q01.w, xw1, rw1)
        AGG_CALC(q23.x, q23.y, xw2, rw2)
        AGG_CALC(q23.z, q23.w, xw3, rw3)
        AGG_CALC(q45.x, q45.y, xw4, rw4)
        AGG_CALC(q45.z, q45.w, xw5, rw5)
        AGG_CALC(q67.x, q67.y, xw6, rw6)
        AGG_CALC(q67.z, q67.w, xw7, rw7)
    }
    if (j + 3 < end) {   // 4-wide
        uint4 q01 = *(const uint4*)(erec + j);
        uint4 q23 = *(const uint4*)(erec + j + 2);
        unsigned xw0 = xb[((q01.x & 0xffffu) << 6) + lane];
        unsigned rw0 = rb[(((q01.x >> 16) & 0x7fffu) << 6) + lane];
        unsigned xw1 = xb[((q01.z & 0xffffu) << 6) + lane];
        unsigned rw1 = rb[(((q01.z >> 16) & 0x7fffu) << 6) + lane];
        unsigned xw2 = xb[((q23.x & 0xffffu) << 6) + lane];
        unsigned rw2 = rb[(((q23.x >> 16) & 0x7fffu) << 6) + lane];
        unsigned xw3 = xb[((q23.z & 0xffffu) << 6) + lane];
        unsigned rw3 = rb[(((q23.z >> 16) & 0x7fffu) << 6) + lane];
        AGG_CALC(q01.x, q01.y, xw0, rw0)
        AGG_CALC(q01.z, q01.w, xw1, rw1)
        AGG_CALC(q23.x, q23.y, xw2, rw2)
        AGG_CALC(q23.z, q23.w, xw3, rw3)
        j += 4;
    }
    if (j + 1 < end) {   // 2-wide
        uint4 q01 = *(const uint4*)(erec + j);
        unsigned xw0 = xb[((q01.x & 0xffffu) << 6) + lane];
        unsigned rw0 = rb[(((q01.x >> 16) & 0x7fffu) << 6) + lane];
        unsigned xw1 = xb[((q01.z & 0xffffu) << 6) + lane];
        unsigned rw1 = rb[(((q01.z >> 16) & 0x7fffu) << 6) + lane];
        AGG_CALC(q01.x, q01.y, xw0, rw0)
        AGG_CALC(q01.z, q01.w, xw1, rw1)
        j += 2;
    }
    if (j < end) {       // last single
        uint2 e0 = erec[j];
        unsigned xw0 = xb[((e0.x & 0xffffu) << 6) + lane];
        unsigned rw0 = rb[(((e0.x >> 16) & 0x7fffu) << 6) + lane];
        AGG_CALC(e0.x, e0.y, xw0, rw0)
    }

    float aI0 = aT0 - aO0, aI1 = aT1 - aO1;
    S_Ob[((unsigned)n << 6) + lane] = f2bfr(aO0) | (f2bfr(aO1) << 16);
    S_Ib[((unsigned)n << 6) + lane] = f2bfr(aI0) | (f2bfr(aI1) << 16);
    if (lane == 0) { cntO[n] = cOf; cntI[n] = (float)deg - cOf; }
}

// ---------------- MFMA GEMM (LDS-staged B) + bias + BN stats ----------------
__global__ __launch_bounds__(256, 4) void gemm_kernel(
    const ushort* __restrict__ xb, const ushort* __restrict__ S_Ob,
    const ushort* __restrict__ S_Ib, const ushort* __restrict__ Wb,
    const float* __restrict__ bias0, const float* __restrict__ bO3,
    const float* __restrict__ bI3, const float* __restrict__ cntO,
    const float* __restrict__ cntI, float* __restrict__ y,
    float* __restrict__ colsum, float* __restrict__ colsq) {
    __shared__ ushort Bs[128][136];   // 34.8 KB, row stride 272 B
    __shared__ float redS[4][128];
    __shared__ float redQ[4][128];

    int tid = threadIdx.x;
    int wv = tid >> 6, lane = tid & 63;
    int cl = lane & 15, kg = lane >> 4;
    int wrow0 = blockIdx.x * 64 + wv * 16;

    f32x4 acc[8];
#pragma unroll
    for (int cf = 0; cf < 8; ++cf) acc[cf] = (f32x4){0.f, 0.f, 0.f, 0.f};

    int rowA = wrow0 + cl;
    int rowc = rowA < N_NODES ? rowA : N_NODES - 1;
    const ushort* Abase[3] = {xb, S_Ob, S_Ib};

    for (int kq = 0; kq < 3; ++kq) {
        __syncthreads();
#pragma unroll
        for (int j = 0; j < 8; ++j) {
            int i = tid + j * 256;
            int col = i >> 4, k8 = (i & 15) << 3;
            uint4 w = *(const uint4*)(Wb + (size_t)col * 384 + kq * 128 + k8);
            *(uint4*)&Bs[col][k8] = w;
        }
        const ushort* Ap0 = Abase[kq] + (size_t)rowc * 128 + kg * 8;
        uint4 a4[4];
#pragma unroll
        for (int ks = 0; ks < 4; ++ks) a4[ks] = *(const uint4*)(Ap0 + ks * 32);
        __syncthreads();
#pragma unroll
        for (int ks = 0; ks < 4; ++ks) {
            bf16x8 af = __builtin_bit_cast(bf16x8, a4[ks]);
#pragma unroll
            for (int cf = 0; cf < 8; ++cf) {
                bf16x8 bv = __builtin_bit_cast(bf16x8,
                    *(const uint4*)&Bs[cf * 16 + cl][ks * 32 + kg * 8]);
                acc[cf] = __builtin_amdgcn_mfma_f32_16x16x32_bf16(af, bv, acc[cf], 0, 0, 0);
            }
        }
    }

    float b0a[8], boa[8], bia[8];
#pragma unroll
    for (int cf = 0; cf < 8; ++cf) {
        int col = cf * 16 + cl;
        b0a[cf] = bias0[col]; boa[cf] = bO3[col]; bia[cf] = bI3[col];
    }
    float cOv[4], cIv[4]; int rows[4]; bool rv[4];
#pragma unroll
    for (int r = 0; r < 4; ++r) {
        int row = wrow0 + kg * 4 + r;
        rows[r] = row; rv[r] = row < N_NODES;
        cOv[r] = rv[r] ? cntO[row] : 0.f;
        cIv[r] = rv[r] ? cntI[row] : 0.f;
    }
    float ps[8], pq[8];
#pragma unroll
    for (int cf = 0; cf < 8; ++cf) {
        float s = 0.f, q = 0.f;
        int col = cf * 16 + cl;
#pragma unroll
        for (int r = 0; r < 4; ++r) {
            if (rv[r]) {
                float v = acc[cf][r] + b0a[cf] + cOv[r] * boa[cf] + cIv[r] * bia[cf];
                y[(size_t)rows[r] * DIM + col] = v;
                s += v; q += v * v;
            }
        }
        s += __shfl_xor(s, 16);
        s += __shfl_xor(s, 32);
        q += __shfl_xor(q, 16);
        q += __shfl_xor(q, 32);
        ps[cf] = s; pq[cf] = q;
    }
    if (kg == 0) {
#pragma unroll
        for (int cf = 0; cf < 8; ++cf) {
            redS[wv][cf * 16 + cl] = ps[cf];
            redQ[wv][cf * 16 + cl] = pq[cf];
        }
    }
    __syncthreads();
    if (tid < 128) {
        float s = redS[0][tid] + redS[1][tid] + redS[2][tid] + redS[3][tid];
        float q = redQ[0][tid] + redQ[1][tid] + redQ[2][tid] + redQ[3][tid];
        atomicAdd(colsum + tid, s);
        atomicAdd(colsq + tid, q);
    }
}

// BN + tanh, in place on y.
__global__ __launch_bounds__(256) void bn_apply_kernel(
    float* __restrict__ y, const float* __restrict__ colsum, const float* __restrict__ colsq,
    const float* __restrict__ gamma, const float* __restrict__ beta) {
    __shared__ __align__(16) float sc[DIM];
    __shared__ __align__(16) float sh[DIM];
    int tid = threadIdx.x;
    if (tid < DIM) {
        float mean = colsum[tid] * (1.0f / N_NODES);
        float var  = colsq[tid] * (1.0f / N_NODES) - mean * mean;
        float s = rsqrtf(var + BN_EPS) * gamma[tid];
        sc[tid] = s;
        sh[tid] = beta[tid] - mean * s;
    }
    __syncthreads();
    const int total4 = N_NODES * 32;
    for (int i = blockIdx.x * 256 + tid; i < total4; i += gridDim.x * 256) {
        float4 s4 = ((const float4*)sc)[i & 31];
        float4 h4 = ((const float4*)sh)[i & 31];
        float4 v = ((float4*)y)[i];
        v.x = tanhf(v.x * s4.x + h4.x);
        v.y = tanhf(v.y * s4.y + h4.y);
        v.z = tanhf(v.z * s4.z + h4.z);
        v.w = tanhf(v.w * s4.w + h4.w);
        ((float4*)y)[i] = v;
    }
}

extern "C" void kernel_launch(void* const* d_in, const int* in_sizes, int n_in,
                              void* d_out, int out_size, void* d_ws, size_t ws_size,
                              hipStream_t stream) {
    const float* x        = (const float*)d_in[0];
    const float* r_feats  = (const float*)d_in[1];
    const int*   src      = (const int*)d_in[2];
    const int*   dst      = (const int*)d_in[3];
    const int*   etype    = (const int*)d_in[4];
    const float* norm     = (const float*)d_in[5];
    const void*  in_mask  = d_in[6];
    const void*  out_mask = d_in[7];
    const float* W_O_w    = (const float*)d_in[8];
    const float* W_O_b    = (const float*)d_in[9];
    const float* W_I_w    = (const float*)d_in[10];
    const float* W_I_b    = (const float*)d_in[11];
    const float* W_S_w    = (const float*)d_in[12];
    const float* W_S_b    = (const float*)d_in[13];
    const float* W_R_w    = (const float*)d_in[14];
    const float* W_R_b    = (const float*)d_in[15];
    const float* loop_rel = (const float*)d_in[16];
    const float* bn_gamma = (const float*)d_in[17];
    const float* bn_beta  = (const float*)d_in[18];

    const size_t ND = (size_t)N_NODES * DIM;
    char* p = (char*)d_ws;
    auto alloc = [&](size_t bytes) { void* r = (void*)p; p += (bytes + 255) & ~(size_t)255; return r; };

    ushort* S_Ob = (ushort*)alloc(ND * 2);
    ushort* S_Ib = (ushort*)alloc(ND * 2);
    ushort* xb   = (ushort*)alloc(ND * 2);
    ushort* rb   = (ushort*)alloc((size_t)R_REL * DIM * 2);
    uint2* erec  = (uint2*)alloc((size_t)N_NODES * SLOTS * 8);  // 25.6 MB slotted
    ushort* Wb   = (ushort*)alloc((size_t)DIM * 384 * 2);
    float* bias0 = (float*)alloc(DIM * 4);
    float* bO3   = (float*)alloc(DIM * 4);
    float* bI3   = (float*)alloc(DIM * 4);
    float* colsum= (float*)alloc(DIM * 4);
    float* colsq = (float*)alloc(DIM * 4);
    float* cntO  = (float*)alloc(N_NODES * 4);
    float* cntI  = (float*)alloc(N_NODES * 4);
    int*   cnt   = (int*)alloc(N_NODES * 4);
    int*   flag  = (int*)alloc(4);

    float* y    = (float*)d_out;               // n_out region, N*D floats
    float* rout = (float*)d_out + ND;          // r_out region, R*D floats

    init0_kernel<<<(N_NODES + 255) / 256, 256, 0, stream>>>(
        cnt, (const unsigned char*)in_mask, (const unsigned char*)out_mask, flag);

    fused_front_kernel<<<NB_TOTAL, 256, 0, stream>>>(
        dst, src, etype, norm, out_mask, flag, cnt, erec,
        x, xb, r_feats, rb,
        W_O_w, W_I_w, W_S_w, loop_rel, W_S_b, W_O_b, W_I_b,
        Wb, bias0, bO3, bI3, colsum, colsq,
        W_R_w, W_R_b, rout);

    aggregate_kernel<<<(N_NODES + 3) / 4, 256, 0, stream>>>(
        (const unsigned int*)xb, (const unsigned int*)rb, erec, cnt,
        (unsigned int*)S_Ob, (unsigned int*)S_Ib, cntO, cntI);

    gemm_kernel<<<(N_NODES + 63) / 64, 256, 0, stream>>>(
        xb, S_Ob, S_Ib, Wb, bias0, bO3, bI3, cntO, cntI, y, colsum, colsq);

    bn_apply_kernel<<<2048, 256, 0, stream>>>(y, colsum, colsq, bn_gamma, bn_beta);
}